// Round 7
// baseline (235.048 us; speedup 1.0000x reference)
//
#include <hip/hip_runtime.h>
#include <math.h>

// Problem constants (fixed by the reference setup_inputs()).
#define TT 3
#define NN 50000
#define DD 64
#define EE 800000
#define LL 2
#define NK3 (NN * TT)              // 150000 (row,tau) CSR keys
#define NB3 ((NK3 + 255) / 256)    // 586 scan blocks
#define CH 96                      // k_edge LDS chunk (>= max node degree)

typedef _Float16 h4 __attribute__((ext_vector_type(4)));
typedef float f4 __attribute__((ext_vector_type(4)));

// ---------------------------------------------------------------------------
// k_small: O(T*D) edge-feature transforms for BOTH layers + f16 B matrices.
// ---------------------------------------------------------------------------
__global__ void k_small(const float* __restrict__ ef0,
                        const float* __restrict__ tg,   // [L,T,D]
                        const float* __restrict__ wr,   // [L,D,D]
                        const float* __restrict__ we,   // [L,D,D]
                        const float* __restrict__ thj,  // [L,T,D]
                        float* __restrict__ rg,         // [L*T*T]
                        float* __restrict__ sig,        // [L*T*D]
                        _Float16* __restrict__ bf)      // [L*80*64] Bt[c][k]
{
    __shared__ float ef_l[TT * DD];
    __shared__ float efn[TT * DD];
    int tid = threadIdx.x;
    // precompute f16 B = [we^T cols | thj rows | 0] for both layers
    for (int l = 0; l < LL; ++l)
        for (int idx = tid; idx < 80 * 64; idx += 256) {
            int c = idx >> 6, k = idx & 63;
            float v = 0.f;
            if (c < 64) v = we[l * 4096 + k * 64 + c];
            else if (c < 67) v = thj[l * 192 + (c - 64) * 64 + k];
            bf[l * 5120 + idx] = (_Float16)v;
        }
    if (tid < TT * DD) ef_l[tid] = ef0[tid];
    __syncthreads();
    for (int layer = 0; layer < LL; ++layer) {
        if (tid < TT * TT) {
            int t = tid / TT, tau = tid % TT;
            float s = 0.f;
            #pragma unroll
            for (int k = 0; k < DD; ++k)
                s += ef_l[tau * DD + k] * tg[layer * TT * DD + t * DD + k];
            rg[layer * TT * TT + tid] = s;
        }
        if (tid < TT * DD) {
            int tau = tid / DD, d = tid % DD;
            float s = 0.f;
            #pragma unroll
            for (int k = 0; k < DD; ++k)
                s += ef_l[tau * DD + k] * wr[layer * DD * DD + k * DD + d];
            efn[tid] = s;
            sig[layer * TT * DD + tid] = 1.f / (1.f + expf(-s));
        }
        __syncthreads();
        if (tid < TT * DD) ef_l[tid] = fmaxf(efn[tid], 0.f);
        __syncthreads();
    }
}

// ---------------------------------------------------------------------------
// CSR over (row, etype) keys.
// ---------------------------------------------------------------------------
__global__ void k_count3(const int* __restrict__ row, const int* __restrict__ et,
                         int* __restrict__ counts)
{
    int e = blockIdx.x * 256 + threadIdx.x;
    if (e < EE) atomicAdd(&counts[row[e] * 3 + et[e]], 1);
}

__global__ void k_bsum(const int* __restrict__ counts, int* __restrict__ bsum)
{
    __shared__ int red[256];
    int i = blockIdx.x * 256 + threadIdx.x;
    red[threadIdx.x] = (i < NK3) ? counts[i] : 0;
    __syncthreads();
    for (int off = 128; off >= 1; off >>= 1) {
        if (threadIdx.x < off) red[threadIdx.x] += red[threadIdx.x + off];
        __syncthreads();
    }
    if (threadIdx.x == 0) bsum[blockIdx.x] = red[0];
}

__global__ void k_bscan(int* __restrict__ bsum)
{
    __shared__ int s[1024];
    int tid = threadIdx.x;
    s[tid] = (tid < NB3) ? bsum[tid] : 0;
    __syncthreads();
    for (int off = 1; off < 1024; off <<= 1) {
        int u = (tid >= off) ? s[tid - off] : 0;
        __syncthreads();
        s[tid] += u;
        __syncthreads();
    }
    if (tid < NB3) bsum[tid] = (tid > 0) ? s[tid - 1] : 0;
    if (tid == 0) bsum[NB3] = s[NB3 - 1];
}

__global__ void k_emit(const int* __restrict__ counts,
                       const int* __restrict__ bpre,
                       int* __restrict__ csroff,
                       int* __restrict__ cursor)
{
    __shared__ int s[256];
    int b = blockIdx.x, tid = threadIdx.x;
    int idx = b * 256 + tid;
    int c = (idx < NK3) ? counts[idx] : 0;
    s[tid] = c;
    __syncthreads();
    for (int off = 1; off < 256; off <<= 1) {
        int u = (tid >= off) ? s[tid - off] : 0;
        __syncthreads();
        s[tid] += u;
        __syncthreads();
    }
    if (idx < NK3) {
        int o = bpre[b] + s[tid] - c;
        csroff[idx] = o;
        cursor[idx] = o;
    }
    if (b == 0 && tid == 0) csroff[NK3] = bpre[NB3];
}

__global__ void k_scatter3(const int* __restrict__ row, const int* __restrict__ col,
                           const int* __restrict__ et,
                           int* __restrict__ cursor,
                           unsigned short* __restrict__ pk)
{
    int e = blockIdx.x * 256 + threadIdx.x;
    if (e < EE) {
        int key = row[e] * 3 + et[e];
        int pos = atomicAdd(&cursor[key], 1);
        pk[pos] = (unsigned short)col[e];   // col < 50000 < 2^16
    }
}

// ---------------------------------------------------------------------------
// k_mm: MFMA f16 GEMM  C[rows,80] = h[rows,64] @ Bf (pre-converted f16)
// mode 0: hw layout [n][64] f16.  mode 1: hw layout [n][64][4] (t slot 0-2).
// ---------------------------------------------------------------------------
template <typename TI>
__global__ __launch_bounds__(256) void k_mm(
    const TI* __restrict__ h,         // [rows,64]
    const _Float16* __restrict__ Bf,  // [80*64] Bt[c][k] f16
    _Float16* __restrict__ hw,
    float* __restrict__ ahj,          // [N,4]
    int rows, int mode)               // mode 0: L0, 1: L1 (rows = t*N+n)
{
    __shared__ _Float16 Ah[64][68];
    __shared__ _Float16 Bt[80][68];
    int tid = threadIdx.x;
    long rbase = (long)blockIdx.x * 64;

    #pragma unroll
    for (int it = 0; it < 4; ++it) {
        int flat = (tid + it * 256) * 4;
        int r = flat >> 6, k = flat & 63;
        h4 hv = {};
        if (rbase + r < rows) {
            if constexpr (sizeof(TI) == 4) {
                float4 v = *(const float4*)&h[(rbase + r) * 64 + k];
                hv = h4{ (_Float16)v.x, (_Float16)v.y, (_Float16)v.z, (_Float16)v.w };
            } else {
                hv = *(const h4*)&h[(rbase + r) * 64 + k];
            }
        }
        *(h4*)&Ah[r][k] = hv;
    }
    for (int e4 = tid; e4 < 80 * 64 / 4; e4 += 256) {
        int idx = e4 * 4;
        *(h4*)&Bt[idx >> 6][idx & 63] = *(const h4*)&Bf[idx];
    }
    __syncthreads();

    int wid = tid >> 6, lane = tid & 63;
    int r16 = lane & 15, kq = lane >> 4;
    f4 acc[5] = {};
    #pragma unroll
    for (int ks = 0; ks < 4; ++ks) {
        int k0 = ks * 16 + kq * 4;
        h4 a = *(h4*)&Ah[wid * 16 + r16][k0];
        #pragma unroll
        for (int ct = 0; ct < 5; ++ct) {
            h4 b = *(h4*)&Bt[ct * 16 + r16][k0];
            acc[ct] = __builtin_amdgcn_mfma_f32_16x16x16f16(a, b, acc[ct], 0, 0, 0);
        }
    }
    #pragma unroll
    for (int j = 0; j < 4; ++j) {
        long g = rbase + wid * 16 + kq * 4 + j;
        if (g < rows) {
            int t = 0; long n = g;
            if (mode) {
                t = (g >= 2L * NN) ? 2 : (g >= NN ? 1 : 0);
                n = g - (long)t * NN;
            }
            #pragma unroll
            for (int ct = 0; ct < 4; ++ct) {
                int c = ct * 16 + r16;
                float val = acc[ct][j];
                if (mode) hw[((size_t)n * 64 + c) * 4 + t] = (_Float16)val;
                else      hw[n * 64 + c] = (_Float16)val;
            }
            float av = acc[4][j];
            if (mode) { if (r16 == t) ahj[n * 4 + t] = av; }
            else      { if (r16 < 3)  ahj[n * 4 + r16] = av; }
        }
    }
}

// ---------------------------------------------------------------------------
// k_edge: one NODE per wave, all 3 t's. Flat aggregation loop (tau packed in
// entry bits 26-27) unrolled x4 for max outstanding loads — gather is
// latency-bound (R6 lesson). MODE1: hw is [c][d][4] -> ONE dwordx2 per edge
// fetches all 3 t values. 4 independent waves/block, no barriers.
// ---------------------------------------------------------------------------
template <int MODE>
__global__ __launch_bounds__(256) void k_edge(
    const int* __restrict__ off3,            // [NK3+1]
    const unsigned short* __restrict__ pk,   // [E]
    const float* __restrict__ rg_l,          // [9] r[t][tau]
    const float* __restrict__ sig_l,         // [3*64] (tau,d)
    const float* __restrict__ ahj4,          // [N*4] (t in .x.y.z)
    const _Float16* __restrict__ hw,         // MODE0 [N*64], MODE1 [N*64*4]
    const float* __restrict__ x,
    float* __restrict__ outf,                // MODE1 final f32
    _Float16* __restrict__ outh)             // MODE0 h1 f16
{
    __shared__ uint4 ent[4][CH];
    int wid = threadIdx.x >> 6, lane = threadIdx.x & 63;
    int n = blockIdx.x * 4 + wid;            // NN % 4 == 0, no tail
    int b3 = n * 3;
    int s0 = off3[b3], s1 = off3[b3 + 1], s2 = off3[b3 + 2], s3 = off3[b3 + 3];
    float r00 = rg_l[0], r01 = rg_l[1], r02 = rg_l[2];
    float r10 = rg_l[3], r11 = rg_l[4], r12 = rg_l[5];
    float r20 = rg_l[6], r21 = rg_l[7], r22 = rg_l[8];
    float sg0 = sig_l[lane], sg1 = sig_l[64 + lane], sg2 = sig_l[128 + lane];
    const char* hwb = (const char*)hw + (MODE ? (size_t)lane * 8 : (size_t)lane * 2);
    uint4* myent = ent[wid];
    float acc0 = 0.f, acc1 = 0.f, acc2 = 0.f;
    float ps0 = 0.f, ps1 = 0.f, ps2 = 0.f;

    for (int base = s0; base < s3; base += CH) {
        int cnt = s3 - base; if (cnt > CH) cnt = CH;
        for (int jj = lane; jj < cnt; jj += 64) {
            int ei = base + jj;
            int c = pk[ei];
            int tau = (ei >= s1) + (ei >= s2);
            float4 aj = *(const float4*)&ahj4[c * 4];
            float g0 = (tau == 0) ? r00 : ((tau == 1) ? r01 : r02);
            float g1 = (tau == 0) ? r10 : ((tau == 1) ? r11 : r12);
            float g2 = (tau == 0) ? r20 : ((tau == 1) ? r21 : r22);
            float p0 = __expf(g0 + aj.x);
            float p1 = __expf(g1 + aj.y);
            float p2 = __expf(g2 + aj.z);
            ps0 += p0; ps1 += p1; ps2 += p2;
            unsigned bo = (unsigned)c * (MODE ? 512u : 128u);
            myent[jj] = make_uint4(bo | ((unsigned)tau << 26),
                                   __float_as_uint(p0), __float_as_uint(p1),
                                   __float_as_uint(p2));
        }
        // intra-wave LDS visibility (no cross-wave coupling)
        asm volatile("s_waitcnt lgkmcnt(0)" ::: "memory");

#define AGG(J) { uint4 e = myent[J];                                           \
        unsigned ta = e.x >> 26;                                               \
        float sg = (ta == 0) ? sg0 : ((ta == 1) ? sg1 : sg2);                  \
        const char* ptr = hwb + (e.x & 0x03FFFFFFu);                           \
        if (MODE == 0) {                                                       \
            float sv = sg * (float)*(const _Float16*)ptr;                      \
            acc0 = fmaf(__uint_as_float(e.y), sv, acc0);                       \
            acc1 = fmaf(__uint_as_float(e.z), sv, acc1);                       \
            acc2 = fmaf(__uint_as_float(e.w), sv, acc2);                       \
        } else {                                                               \
            h4 v = *(const h4*)ptr;                                            \
            acc0 = fmaf(__uint_as_float(e.y), sg * (float)v[0], acc0);         \
            acc1 = fmaf(__uint_as_float(e.z), sg * (float)v[1], acc1);         \
            acc2 = fmaf(__uint_as_float(e.w), sg * (float)v[2], acc2);         \
        } }

        int j = 0;
        for (; j + 4 <= cnt; j += 4) { AGG(j) AGG(j + 1) AGG(j + 2) AGG(j + 3) }
        for (; j < cnt; ++j) { AGG(j) }
#undef AGG
        asm volatile("s_waitcnt lgkmcnt(0)" ::: "memory");
    }
    #pragma unroll
    for (int off = 32; off >= 1; off >>= 1) {
        ps0 += __shfl_xor(ps0, off);
        ps1 += __shfl_xor(ps1, off);
        ps2 += __shfl_xor(ps2, off);
    }
    float o0 = 0.f, o1 = 0.f, o2 = 0.f;
    if (s3 > s0) { o0 = acc0 / ps0; o1 = acc1 / ps1; o2 = acc2 / ps2; }
    size_t oi = (size_t)n * 64 + lane;
    if (MODE == 0) {
        float xv = x[oi];
        outh[oi]                       = (_Float16)(xv + fmaxf(o0, 0.f));
        outh[oi + (size_t)NN * 64]     = (_Float16)(xv + fmaxf(o1, 0.f));
        outh[oi + (size_t)2 * NN * 64] = (_Float16)(xv + fmaxf(o2, 0.f));
    } else {
        outf[oi]                       = o0;
        outf[oi + (size_t)NN * 64]     = o1;
        outf[oi + (size_t)2 * NN * 64] = o2;
    }
}

// ---------------------------------------------------------------------------
extern "C" void kernel_launch(void* const* d_in, const int* in_sizes, int n_in,
                              void* d_out, int out_size, void* d_ws, size_t ws_size,
                              hipStream_t stream)
{
    const float* x   = (const float*)d_in[0];
    const int*   ei  = (const int*)d_in[1];
    const int*   row = ei;
    const int*   col = ei + EE;
    const int*   et  = (const int*)d_in[2];
    const float* ef  = (const float*)d_in[3];
    const float* tg  = (const float*)d_in[4];
    // d_in[5] = theta_hi: cancels in scatter-softmax (constant per group)
    const float* thj = (const float*)d_in[6];
    const float* we  = (const float*)d_in[7];
    const float* wr  = (const float*)d_in[8];
    float* out = (float*)d_out;
    _Float16* h1h = (_Float16*)d_out;   // h1 staged as f16 in d_out

    // workspace layout
    _Float16* hw1 = (_Float16*)d_ws;                      // N*64*4 (t-slotted)
    _Float16* hw0 = hw1 + (size_t)NN * 64 * 4;            // N*64
    float* ahj  = (float*)(hw0 + (size_t)NN * 64);        // N*4
    float* rg   = ahj + (size_t)NN * 4;                   // L*9
    float* sig  = rg + LL * 9;                            // L*192
    _Float16* bfB = (_Float16*)(sig + LL * 192);          // L*80*64 f16
    int* counts3 = (int*)(bfB + LL * 5120);               // NK3
    int* csroff3 = counts3 + NK3;                         // NK3+1
    int* cursor3 = csroff3 + NK3 + 1;                     // NK3
    int* bsum    = cursor3 + NK3;                         // NB3+1
    unsigned short* csrpk = (unsigned short*)(bsum + NB3 + 1);  // E

    hipMemsetAsync(counts3, 0, NK3 * sizeof(int), stream);
    k_small<<<1, 256, 0, stream>>>(ef, tg, wr, we, thj, rg, sig, bfB);
    k_count3<<<(EE + 255) / 256, 256, 0, stream>>>(row, et, counts3);
    k_bsum<<<NB3, 256, 0, stream>>>(counts3, bsum);
    k_bscan<<<1, 1024, 0, stream>>>(bsum);
    k_emit<<<NB3, 256, 0, stream>>>(counts3, bsum, csroff3, cursor3);
    k_scatter3<<<(EE + 255) / 256, 256, 0, stream>>>(row, col, et, cursor3, csrpk);

    // layer 0: h = broadcast(x); h1 = x + relu(out0) written f16 into d_out
    k_mm<float><<<(NN + 63) / 64, 256, 0, stream>>>(x, bfB, hw0, ahj, NN, 0);
    k_edge<0><<<NN / 4, 256, 0, stream>>>(csroff3, csrpk, rg, sig, ahj, hw0,
                                          x, out, h1h);
    // layer 1: reads h1 (f16), writes final f32 over all of d_out
    k_mm<_Float16><<<(NK3 + 63) / 64, 256, 0, stream>>>(h1h, bfB + 5120,
                                                        hw1, ahj, NK3, 1);
    k_edge<1><<<NN / 4, 256, 0, stream>>>(csroff3, csrpk, rg + 9, sig + 192,
                                          ahj, hw1, x, out, nullptr);
}